// Round 2
// baseline (1135.329 us; speedup 1.0000x reference)
//
#include <hip/hip_runtime.h>

typedef unsigned short u16;
typedef __bf16 bf16x8 __attribute__((ext_vector_type(8)));
typedef float  f32x4  __attribute__((ext_vector_type(4)));

#define B_    128
#define C_    512
#define HW_   196
#define A_    2000
#define T_    20
#define E_    300
#define EP_   320
#define LH_   1024
#define MH_   512
#define NG_   4096   // 4*LH

__device__ __forceinline__ u16 f2b(float f) {
    union { float f; unsigned int u; } v; v.f = f;
    unsigned int u = v.u;
    unsigned int r = u + 0x7fffu + ((u >> 16) & 1u);
    return (u16)(r >> 16);
}
__device__ __forceinline__ float b2f(u16 h) {
    union { unsigned int u; float f; } v; v.u = ((unsigned int)h) << 16;
    return v.f;
}
__device__ __forceinline__ float sigmf(float x) { return 1.f / (1.f + __expf(-x)); }

// ---------------------------------------------------------------------------
// Decode yesno robustly: harness may store bool as 1 byte or as int32.
// If byte-packed, the first 32 int32 words almost surely contain a value
// not in {0,1} (P ~ 2^-96 otherwise for random bools). 1 block, 128 thr.
// ---------------------------------------------------------------------------
__global__ void k_decode_yesno(const void* __restrict__ yn_raw, int* __restrict__ yes) {
    __shared__ int bytemode;
    int t = threadIdx.x;
    if (t == 0) bytemode = 0;
    __syncthreads();
    if (t < 32) {
        unsigned int w = ((const unsigned int*)yn_raw)[t];
        if (w > 1u) atomicOr(&bytemode, 1);
    }
    __syncthreads();
    if (t < B_) {
        int v = bytemode ? (int)((const unsigned char*)yn_raw)[t]
                         : ((const int*)yn_raw)[t];
        yes[t] = v ? 1 : 0;
    }
}

// ---------------------------------------------------------------------------
// Find: att = relu(Wsel . features), maps = att0*att1, denom = sum(maps)+1e-6
// ---------------------------------------------------------------------------
__global__ __launch_bounds__(256) void k_find(const float* __restrict__ features,
                                              const int* __restrict__ find_inst,
                                              const float* __restrict__ W_find,
                                              float* __restrict__ maps,
                                              float* __restrict__ denom) {
    __shared__ __align__(16) float w0[C_];
    __shared__ __align__(16) float w1[C_];
    __shared__ float red[256];
    int b = blockIdx.x, t = threadIdx.x;
    int i0 = find_inst[b*2+0], i1 = find_inst[b*2+1];
    w0[t]       = W_find[(size_t)i0*C_ + t];
    w0[t+256]   = W_find[(size_t)i0*C_ + t + 256];
    w1[t]       = W_find[(size_t)i1*C_ + t];
    w1[t+256]   = W_find[(size_t)i1*C_ + t + 256];
    __syncthreads();
    float a0 = 0.f, a1 = 0.f;
    if (t < HW_) {
        const float* f = features + (size_t)b*C_*HW_ + t;
        for (int c = 0; c < C_; c += 4) {
            float4 wv0 = *(const float4*)&w0[c];
            float4 wv1 = *(const float4*)&w1[c];
            float f0 = f[(size_t)c*HW_];
            float f1 = f[(size_t)(c+1)*HW_];
            float f2 = f[(size_t)(c+2)*HW_];
            float f3 = f[(size_t)(c+3)*HW_];
            a0 += wv0.x*f0 + wv0.y*f1 + wv0.z*f2 + wv0.w*f3;
            a1 += wv1.x*f0 + wv1.y*f1 + wv1.z*f2 + wv1.w*f3;
        }
    }
    float m = fmaxf(a0, 0.f) * fmaxf(a1, 0.f);
    if (t < HW_) maps[b*HW_ + t] = m;
    red[t] = (t < HW_) ? m : 0.f;
    __syncthreads();
    for (int s = 128; s > 0; s >>= 1) { if (t < s) red[t] += red[t+s]; __syncthreads(); }
    if (t == 0) denom[b] = red[0] + 1e-6f;
}

// ---------------------------------------------------------------------------
// attended[b,c] = sum_hw (maps/denom) * features
// grid: 128*4 blocks; block covers 128 channels
// ---------------------------------------------------------------------------
__global__ __launch_bounds__(256) void k_attended(const float* __restrict__ features,
                                                  const float* __restrict__ maps,
                                                  const float* __restrict__ denom,
                                                  float* __restrict__ attended) {
    __shared__ float ml[HW_];
    int b = blockIdx.x >> 2, cc = blockIdx.x & 3;
    int t = threadIdx.x, wave = t >> 6, lane = t & 63;
    if (t < HW_) ml[t] = maps[b*HW_ + t];
    __syncthreads();
    float dn = denom[b];
    for (int ci = 0; ci < 32; ci++) {
        int c = cc*128 + ci*4 + wave;
        const float* f = features + ((size_t)b*C_ + c)*HW_;
        float p = ml[lane]*f[lane] + ml[lane+64]*f[lane+64] + ml[lane+128]*f[lane+128];
        if (lane < 4) p += ml[192+lane]*f[192+lane];
        for (int off = 32; off > 0; off >>= 1) p += __shfl_down(p, off, 64);
        if (lane == 0) attended[b*C_ + c] = p / dn;
    }
}

// ---------------------------------------------------------------------------
// measure hidden: h = relu(mflat @ W_meas1[r] + b_meas1[r])  (yes samples only)
// ---------------------------------------------------------------------------
__global__ __launch_bounds__(256) void k_meas_h(const int* __restrict__ yes,
                                                const int* __restrict__ root_inst,
                                                const float* __restrict__ maps,
                                                const float* __restrict__ W_meas1,
                                                const float* __restrict__ b_meas1,
                                                float* __restrict__ h_ws) {
    int b = blockIdx.x;
    if (!yes[b]) return;
    __shared__ __align__(16) float mf[HW_];
    int t = threadIdx.x;
    if (t < HW_) mf[t] = maps[b*HW_ + t];
    __syncthreads();
    int r = root_inst[b];
    const float* W = W_meas1 + (size_t)r*HW_*MH_;
    float acc0 = b_meas1[r*MH_ + t];
    float acc1 = b_meas1[r*MH_ + t + 256];
    for (int i = 0; i < HW_; i += 2) {
        float m0 = mf[i], m1 = mf[i+1];
        acc0 += m0*W[(size_t)i*MH_ + t]       + m1*W[(size_t)(i+1)*MH_ + t];
        acc1 += m0*W[(size_t)i*MH_ + t + 256] + m1*W[(size_t)(i+1)*MH_ + t + 256];
    }
    h_ws[b*MH_ + t]       = fmaxf(acc0, 0.f);
    h_ws[b*MH_ + t + 256] = fmaxf(acc1, 0.f);
}

// ---------------------------------------------------------------------------
// yes_logits = h @ W_meas2 + b_meas2   (grid 128*8)
// ---------------------------------------------------------------------------
__global__ __launch_bounds__(256) void k_yes_logits(const int* __restrict__ yes,
                                                    const float* __restrict__ h_ws,
                                                    const float* __restrict__ W_meas2,
                                                    const float* __restrict__ b_meas2,
                                                    float* __restrict__ root_logits) {
    int b = blockIdx.x >> 3, ch = blockIdx.x & 7;
    if (!yes[b]) return;
    __shared__ __align__(16) float h[MH_];
    int t = threadIdx.x;
    h[t]     = h_ws[b*MH_ + t];
    h[t+256] = h_ws[b*MH_ + t + 256];
    __syncthreads();
    int a = ch*256 + t;
    if (a >= A_) return;
    float acc = b_meas2[a];
    for (int k = 0; k < MH_; k += 4) {
        float4 hv = *(const float4*)&h[k];
        acc += hv.x*W_meas2[(size_t)k*A_ + a]     + hv.y*W_meas2[(size_t)(k+1)*A_ + a]
             + hv.z*W_meas2[(size_t)(k+2)*A_ + a] + hv.w*W_meas2[(size_t)(k+3)*A_ + a];
    }
    root_logits[b*A_ + a] = acc;
}

// ---------------------------------------------------------------------------
// other_logits = attended @ W_desc[r] + b_desc[r]   (no samples, grid 128*8)
// ---------------------------------------------------------------------------
__global__ __launch_bounds__(256) void k_other_logits(const int* __restrict__ yes,
                                                      const int* __restrict__ root_inst,
                                                      const float* __restrict__ attended,
                                                      const float* __restrict__ W_desc,
                                                      const float* __restrict__ b_desc,
                                                      float* __restrict__ root_logits) {
    int b = blockIdx.x >> 3, ch = blockIdx.x & 7;
    if (yes[b]) return;
    __shared__ __align__(16) float at[C_];
    int t = threadIdx.x;
    at[t]     = attended[b*C_ + t];
    at[t+256] = attended[b*C_ + t + 256];
    __syncthreads();
    int a = ch*256 + t;
    if (a >= A_) return;
    int r = root_inst[b];
    const float* W = W_desc + (size_t)r*C_*A_;
    float acc = b_desc[r*A_ + a];
    for (int k = 0; k < C_; k += 4) {
        float4 hv = *(const float4*)&at[k];
        acc += hv.x*W[(size_t)k*A_ + a]     + hv.y*W[(size_t)(k+1)*A_ + a]
             + hv.z*W[(size_t)(k+2)*A_ + a] + hv.w*W[(size_t)(k+3)*A_ + a];
    }
    root_logits[b*A_ + a] = acc;
}

// ---------------------------------------------------------------------------
// embedding gather + bf16 cast + K-pad to 320
// ---------------------------------------------------------------------------
__global__ __launch_bounds__(256) void k_embed(const int* __restrict__ question,
                                               const float* __restrict__ E_emb,
                                               u16* __restrict__ Xbf) {
    int gid = blockIdx.x*256 + threadIdx.x;
    if (gid >= B_*T_*EP_) return;
    int row = gid / EP_, k = gid % EP_;
    int q = question[row];
    float v = (k < E_) ? E_emb[(size_t)q*E_ + k] : 0.f;
    Xbf[gid] = f2b(v);
}

// ---------------------------------------------------------------------------
// transpose + bf16 cast: dst[n*K_pad + k] = src[k*N_src + n]  (zero pad)
// grid: (K_pad/64, N_dst/64), 256 threads
// ---------------------------------------------------------------------------
__global__ __launch_bounds__(256) void k_transpose_cast(const float* __restrict__ src,
                                                        u16* __restrict__ dst,
                                                        int K_src, int N_src, int K_pad) {
    __shared__ float tile[64][65];
    int kb = blockIdx.x * 64, nb = blockIdx.y * 64;
    int t = threadIdx.x, tc = t & 63, tr = t >> 6;
    for (int rr = 0; rr < 16; rr++) {
        int k = kb + tr + rr*4;
        int n = nb + tc;
        float v = (k < K_src && n < N_src) ? src[(size_t)k*N_src + n] : 0.f;
        tile[tr + rr*4][tc] = v;
    }
    __syncthreads();
    for (int rr = 0; rr < 16; rr++) {
        int n = nb + tr + rr*4;
        dst[(size_t)n*K_pad + kb + tc] = f2b(tile[tc][tr + rr*4]);
    }
}

// ---------------------------------------------------------------------------
// zx = Xbf @ WxT^T + b_lstm   -> bf16 [2560][4096]
// grid (20, 32): 128x128 tiles, K=320
// ---------------------------------------------------------------------------
__global__ __launch_bounds__(256) void k_gemm_zx(const u16* __restrict__ Xbf,
                                                 const u16* __restrict__ WxT,
                                                 const float* __restrict__ b_lstm,
                                                 u16* __restrict__ zx) {
    __shared__ __align__(16) u16 As[128][32];
    __shared__ __align__(16) u16 Bs[128][32];
    int bm = blockIdx.x, bn = blockIdx.y;
    int t = threadIdx.x, wave = t >> 6, lane = t & 63;
    int lm = lane & 15, lq = lane >> 4;
    int wr = (wave >> 1) * 64, wc = (wave & 1) * 64;
    f32x4 acc[4][4] = {};
    for (int kc = 0; kc < EP_; kc += 32) {
        for (int s = t; s < 512; s += 256) {
            int row = s >> 2, off = (s & 3) << 3;
            *(int4*)&As[row][off] = *(const int4*)&Xbf[(size_t)(bm*128 + row)*EP_ + kc + off];
            *(int4*)&Bs[row][off] = *(const int4*)&WxT[(size_t)(bn*128 + row)*EP_ + kc + off];
        }
        __syncthreads();
        bf16x8 af[4], bfr[4];
        for (int i = 0; i < 4; i++) af[i]  = *(const bf16x8*)&As[wr + i*16 + lm][lq*8];
        for (int j = 0; j < 4; j++) bfr[j] = *(const bf16x8*)&Bs[wc + j*16 + lm][lq*8];
        for (int i = 0; i < 4; i++)
            for (int j = 0; j < 4; j++)
                acc[i][j] = __builtin_amdgcn_mfma_f32_16x16x32_bf16(af[i], bfr[j], acc[i][j], 0, 0, 0);
        __syncthreads();
    }
    for (int i = 0; i < 4; i++)
        for (int j = 0; j < 4; j++) {
            int col = bn*128 + wc + j*16 + lm;
            float bias = b_lstm[col];
            for (int r = 0; r < 4; r++) {
                int row = bm*128 + wr + i*16 + lq*4 + r;
                zx[(size_t)row*NG_ + col] = f2b(acc[i][j][r] + bias);
            }
        }
}

// ---------------------------------------------------------------------------
// one LSTM step: z = hprev @ Wh^T (+zx), gates, update c/h, record h_last
// grid 128 blocks: block nb covers hidden units j0..j0+7 (32 gate columns)
// ---------------------------------------------------------------------------
__global__ __launch_bounds__(256) void k_lstm_step(const u16* __restrict__ hprev,
                                                   const u16* __restrict__ WhT,
                                                   const u16* __restrict__ zx,
                                                   float* __restrict__ cst,
                                                   u16* __restrict__ hnext,
                                                   u16* __restrict__ h_last,
                                                   const int* __restrict__ length,
                                                   int tstep) {
    __shared__ __align__(16) u16 As[128][32];
    __shared__ __align__(16) u16 Bs[32][32];
    __shared__ float Zs[128][32];
    int nb = blockIdx.x;
    int j0 = nb * 8;
    int t = threadIdx.x, wave = t >> 6, lane = t & 63;
    int lm = lane & 15, lq = lane >> 4;
    int wr = wave * 32;
    f32x4 a00 = {}, a01 = {}, a10 = {}, a11 = {};
    for (int kc = 0; kc < LH_; kc += 32) {
        for (int s = t; s < 512; s += 256) {
            int row = s >> 2, off = (s & 3) << 3;
            *(int4*)&As[row][off] = *(const int4*)&hprev[(size_t)row*LH_ + kc + off];
        }
        if (t < 128) {
            int nl = t >> 2, off = (t & 3) << 3;
            int grow = ((nl >> 3) << 10) + j0 + (nl & 7);  // g*1024 + j
            *(int4*)&Bs[nl][off] = *(const int4*)&WhT[(size_t)grow*LH_ + kc + off];
        }
        __syncthreads();
        bf16x8 af0 = *(const bf16x8*)&As[wr + lm][lq*8];
        bf16x8 af1 = *(const bf16x8*)&As[wr + 16 + lm][lq*8];
        bf16x8 bf0 = *(const bf16x8*)&Bs[lm][lq*8];
        bf16x8 bf1 = *(const bf16x8*)&Bs[16 + lm][lq*8];
        a00 = __builtin_amdgcn_mfma_f32_16x16x32_bf16(af0, bf0, a00, 0, 0, 0);
        a01 = __builtin_amdgcn_mfma_f32_16x16x32_bf16(af0, bf1, a01, 0, 0, 0);
        a10 = __builtin_amdgcn_mfma_f32_16x16x32_bf16(af1, bf0, a10, 0, 0, 0);
        a11 = __builtin_amdgcn_mfma_f32_16x16x32_bf16(af1, bf1, a11, 0, 0, 0);
        __syncthreads();
    }
    for (int r = 0; r < 4; r++) {
        Zs[wr + lq*4 + r][lm]           = a00[r];
        Zs[wr + lq*4 + r][16 + lm]      = a01[r];
        Zs[wr + 16 + lq*4 + r][lm]      = a10[r];
        Zs[wr + 16 + lq*4 + r][16 + lm] = a11[r];
    }
    __syncthreads();
    for (int it = 0; it < 4; it++) {
        int idx = t + it*256;
        int b = idx >> 3, jj = idx & 7;
        int j = j0 + jj;
        size_t zrow = (size_t)(b*T_ + tstep) * NG_;
        float zi = Zs[b][jj]      + b2f(zx[zrow + j]);
        float zf = Zs[b][8 + jj]  + b2f(zx[zrow + 1024 + j]);
        float zg = Zs[b][16 + jj] + b2f(zx[zrow + 2048 + j]);
        float zo = Zs[b][24 + jj] + b2f(zx[zrow + 3072 + j]);
        float cp = cst[b*LH_ + j];
        float cn = sigmf(zf)*cp + sigmf(zi)*tanhf(zg);
        float hn = sigmf(zo)*tanhf(cn);
        cst[b*LH_ + j] = cn;
        hnext[b*LH_ + j] = f2b(hn);
        if (length[b] - 1 == tstep) h_last[b*LH_ + j] = f2b(hn);
    }
}

// ---------------------------------------------------------------------------
// enc_logits = h_last @ W_enc + b_enc via MFMA; grid 64 blocks (2048/32)
// ---------------------------------------------------------------------------
__global__ __launch_bounds__(256) void k_enc_gemm(const u16* __restrict__ h_last,
                                                  const u16* __restrict__ WencT,
                                                  const float* __restrict__ b_enc,
                                                  float* __restrict__ enc_logits) {
    __shared__ __align__(16) u16 As[128][32];
    __shared__ __align__(16) u16 Bs[32][32];
    __shared__ float Zs[128][32];
    int n0 = blockIdx.x * 32;
    int t = threadIdx.x, wave = t >> 6, lane = t & 63;
    int lm = lane & 15, lq = lane >> 4;
    int wr = wave * 32;
    f32x4 a00 = {}, a01 = {}, a10 = {}, a11 = {};
    for (int kc = 0; kc < LH_; kc += 32) {
        for (int s = t; s < 512; s += 256) {
            int row = s >> 2, off = (s & 3) << 3;
            *(int4*)&As[row][off] = *(const int4*)&h_last[(size_t)row*LH_ + kc + off];
        }
        if (t < 128) {
            int nl = t >> 2, off = (t & 3) << 3;
            *(int4*)&Bs[nl][off] = *(const int4*)&WencT[(size_t)(n0 + nl)*LH_ + kc + off];
        }
        __syncthreads();
        bf16x8 af0 = *(const bf16x8*)&As[wr + lm][lq*8];
        bf16x8 af1 = *(const bf16x8*)&As[wr + 16 + lm][lq*8];
        bf16x8 bf0 = *(const bf16x8*)&Bs[lm][lq*8];
        bf16x8 bf1 = *(const bf16x8*)&Bs[16 + lm][lq*8];
        a00 = __builtin_amdgcn_mfma_f32_16x16x32_bf16(af0, bf0, a00, 0, 0, 0);
        a01 = __builtin_amdgcn_mfma_f32_16x16x32_bf16(af0, bf1, a01, 0, 0, 0);
        a10 = __builtin_amdgcn_mfma_f32_16x16x32_bf16(af1, bf0, a10, 0, 0, 0);
        a11 = __builtin_amdgcn_mfma_f32_16x16x32_bf16(af1, bf1, a11, 0, 0, 0);
        __syncthreads();
    }
    for (int r = 0; r < 4; r++) {
        Zs[wr + lq*4 + r][lm]           = a00[r];
        Zs[wr + lq*4 + r][16 + lm]      = a01[r];
        Zs[wr + 16 + lq*4 + r][lm]      = a10[r];
        Zs[wr + 16 + lq*4 + r][16 + lm] = a11[r];
    }
    __syncthreads();
    for (int it = 0; it < 16; it++) {
        int idx = t + it*256;
        int b = idx >> 5, nl = idx & 31;
        int a = n0 + nl;
        if (a < A_) enc_logits[b*A_ + a] = Zs[b][nl] + b_enc[a];
    }
}

// ---------------------------------------------------------------------------
// final: softmax(root_logits) , softmax(enc_logits), out = sqrt(p_r * p_e)
// ---------------------------------------------------------------------------
__global__ __launch_bounds__(256) void k_final(const float* __restrict__ root_logits,
                                               const float* __restrict__ enc_logits,
                                               float* __restrict__ out) {
    __shared__ float red[256];
    int b = blockIdx.x, t = threadIdx.x;
    const float* rl = root_logits + b*A_;
    const float* el = enc_logits + b*A_;
    float m = -1e30f;
    for (int i = t; i < A_; i += 256) m = fmaxf(m, rl[i]);
    red[t] = m; __syncthreads();
    for (int s = 128; s > 0; s >>= 1) { if (t < s) red[t] = fmaxf(red[t], red[t+s]); __syncthreads(); }
    float mr = red[0]; __syncthreads();
    float sum = 0.f;
    for (int i = t; i < A_; i += 256) sum += __expf(rl[i] - mr);
    red[t] = sum; __syncthreads();
    for (int s = 128; s > 0; s >>= 1) { if (t < s) red[t] += red[t+s]; __syncthreads(); }
    float sr = red[0]; __syncthreads();
    m = -1e30f;
    for (int i = t; i < A_; i += 256) m = fmaxf(m, el[i]);
    red[t] = m; __syncthreads();
    for (int s = 128; s > 0; s >>= 1) { if (t < s) red[t] = fmaxf(red[t], red[t+s]); __syncthreads(); }
    float me = red[0]; __syncthreads();
    sum = 0.f;
    for (int i = t; i < A_; i += 256) sum += __expf(el[i] - me);
    red[t] = sum; __syncthreads();
    for (int s = 128; s > 0; s >>= 1) { if (t < s) red[t] += red[t+s]; __syncthreads(); }
    float se = red[0];
    float inv = 1.f / (sr * se);
    for (int i = t; i < A_; i += 256)
        out[b*A_ + i] = sqrtf(__expf(rl[i] - mr) * __expf(el[i] - me) * inv);
}

// ---------------------------------------------------------------------------
extern "C" void kernel_launch(void* const* d_in, const int* in_sizes, int n_in,
                              void* d_out, int out_size, void* d_ws, size_t ws_size,
                              hipStream_t stream) {
    const float* features  = (const float*)d_in[0];
    const int*   question  = (const int*)d_in[1];
    const int*   length    = (const int*)d_in[2];
    const void*  yesno_raw = d_in[3];
    const int*   root_inst = (const int*)d_in[4];
    const int*   find_inst = (const int*)d_in[5];
    const float* W_find    = (const float*)d_in[6];
    const float* W_meas1   = (const float*)d_in[7];
    const float* b_meas1   = (const float*)d_in[8];
    const float* W_meas2   = (const float*)d_in[9];
    const float* b_meas2   = (const float*)d_in[10];
    const float* W_desc    = (const float*)d_in[11];
    const float* b_desc    = (const float*)d_in[12];
    const float* E_emb     = (const float*)d_in[13];
    const float* Wx        = (const float*)d_in[14];
    const float* Wh        = (const float*)d_in[15];
    const float* b_lstm    = (const float*)d_in[16];
    const float* W_enc     = (const float*)d_in[17];
    const float* b_enc     = (const float*)d_in[18];
    float* out = (float*)d_out;

    char* wptr = (char*)d_ws;
    auto take = [&](size_t n) { char* p = wptr; wptr += (n + 255) & ~(size_t)255; return (void*)p; };
    float* maps        = (float*)take((size_t)B_*HW_*4);
    float* denom       = (float*)take((size_t)B_*4);
    float* attended    = (float*)take((size_t)B_*C_*4);
    float* h_meas      = (float*)take((size_t)B_*MH_*4);
    float* root_logits = (float*)take((size_t)B_*A_*4);
    float* enc_logits  = (float*)take((size_t)B_*A_*4);
    int*   yes         = (int*)take((size_t)B_*4);
    u16*   Xbf         = (u16*)take((size_t)B_*T_*EP_*2);
    u16*   WxT         = (u16*)take((size_t)NG_*EP_*2);
    u16*   WhT         = (u16*)take((size_t)NG_*LH_*2);
    u16*   WencT       = (u16*)take((size_t)2048*LH_*2);
    u16*   zx          = (u16*)take((size_t)B_*T_*NG_*2);
    u16*   h0          = (u16*)take((size_t)B_*LH_*2);
    u16*   h1          = (u16*)take((size_t)B_*LH_*2);
    float* cst         = (float*)take((size_t)B_*LH_*4);
    u16*   h_last      = (u16*)take((size_t)B_*LH_*2);

    hipMemsetAsync(h0, 0, (size_t)B_*LH_*2, stream);
    hipMemsetAsync(cst, 0, (size_t)B_*LH_*4, stream);

    k_decode_yesno<<<1, 128, 0, stream>>>(yesno_raw, yes);

    // module network branch
    k_find<<<128, 256, 0, stream>>>(features, find_inst, W_find, maps, denom);
    k_attended<<<512, 256, 0, stream>>>(features, maps, denom, attended);
    k_meas_h<<<128, 256, 0, stream>>>(yes, root_inst, maps, W_meas1, b_meas1, h_meas);
    k_yes_logits<<<1024, 256, 0, stream>>>(yes, h_meas, W_meas2, b_meas2, root_logits);
    k_other_logits<<<1024, 256, 0, stream>>>(yes, root_inst, attended, W_desc, b_desc, root_logits);

    // LSTM branch
    k_embed<<<(B_*T_*EP_ + 255)/256, 256, 0, stream>>>(question, E_emb, Xbf);
    k_transpose_cast<<<dim3(EP_/64, NG_/64), 256, 0, stream>>>(Wx, WxT, E_, NG_, EP_);
    k_transpose_cast<<<dim3(LH_/64, NG_/64), 256, 0, stream>>>(Wh, WhT, LH_, NG_, LH_);
    k_transpose_cast<<<dim3(LH_/64, 2048/64), 256, 0, stream>>>(W_enc, WencT, LH_, A_, LH_);
    k_gemm_zx<<<dim3((B_*T_)/128, NG_/128), 256, 0, stream>>>(Xbf, WxT, b_lstm, zx);
    for (int t = 0; t < T_; t++) {
        const u16* hp = (t & 1) ? h1 : h0;
        u16*       hn = (t & 1) ? h0 : h1;
        k_lstm_step<<<128, 256, 0, stream>>>(hp, WhT, zx, cst, hn, h_last, length, t);
    }
    k_enc_gemm<<<64, 256, 0, stream>>>(h_last, WencT, b_enc, enc_logits);

    k_final<<<128, 256, 0, stream>>>(root_logits, enc_logits, out);
}